// Round 1
// baseline (1214.797 us; speedup 1.0000x reference)
//
#include <hip/hip_runtime.h>

constexpr int N_NODES = 100000;
constexpr int N_EDGES = 600000;
constexpr int D = 128;          // feature dim; OUT_DIM is also 128
constexpr int KC = 32;          // k-chunk for GEMM staging

// ---------------------------------------------------------------------------
// Phase 2: h[row][f] += val * x[col][f]   (32 lanes per edge, float4 gather)
// ---------------------------------------------------------------------------
__global__ __launch_bounds__(256) void scatter_kernel(
    const float* __restrict__ x,
    const int*   __restrict__ rows,
    const int*   __restrict__ cols,
    const float* __restrict__ vals,
    float*       __restrict__ h)
{
    long long gid = (long long)blockIdx.x * blockDim.x + threadIdx.x;
    int e = (int)(gid >> 5);
    if (e >= N_EDGES) return;
    int f = (int)(gid & 31) * 4;

    int r = rows[e];
    int c = cols[e];
    float v = vals[e];

    float4 xv = *reinterpret_cast<const float4*>(x + (size_t)c * D + f);
    float* hp = h + (size_t)r * D + f;
    atomicAdd(hp + 0, v * xv.x);
    atomicAdd(hp + 1, v * xv.y);
    atomicAdd(hp + 2, v * xv.z);
    atomicAdd(hp + 3, v * xv.w);
}

// ---------------------------------------------------------------------------
// Phase 3: out = relu(h @ W[0:128] + x @ W[128:256])
// Block tile: 64 nodes x 128 outputs, 256 threads, per-thread 4x8 register tile.
// k runs 0..255 over concat(h, x); staged in KC=32 chunks through LDS.
// ---------------------------------------------------------------------------
__global__ __launch_bounds__(256) void gemm_relu_kernel(
    const float* __restrict__ h,
    const float* __restrict__ x,
    const float* __restrict__ W,   // [256][128]
    float*       __restrict__ out)
{
    __shared__ float As[64][KC + 1];   // +1 pad breaks bank conflicts
    __shared__ float Ws[KC][128];

    const int block_n0 = blockIdx.x * 64;
    const int tid = threadIdx.x;
    const int tx = tid & 15;          // 16 j-groups of 8
    const int ty = tid >> 4;          // 16 node-groups of 4
    const int j0 = tx * 8;
    const int n0 = ty * 4;

    float acc[4][8];
    #pragma unroll
    for (int i = 0; i < 4; i++)
        #pragma unroll
        for (int j = 0; j < 8; j++) acc[i][j] = 0.f;

    for (int kc = 0; kc < 2 * D; kc += KC) {
        // ---- stage A chunk: 64 nodes x KC values from h (k<128) or x ----
        {
            const float* src = (kc < D) ? h : x;
            const int kbase = kc & (D - 1);
            const int n  = tid >> 2;            // 0..63
            const int kk = (tid & 3) * 8;       // 0,8,16,24
            int nn = block_n0 + n;
            if (nn >= N_NODES) nn = N_NODES - 1;   // clamp (dup read, write guarded)
            const float* sp = src + (size_t)nn * D + kbase + kk;
            float4 a0 = *reinterpret_cast<const float4*>(sp);
            float4 a1 = *reinterpret_cast<const float4*>(sp + 4);
            As[n][kk + 0] = a0.x; As[n][kk + 1] = a0.y;
            As[n][kk + 2] = a0.z; As[n][kk + 3] = a0.w;
            As[n][kk + 4] = a1.x; As[n][kk + 5] = a1.y;
            As[n][kk + 6] = a1.z; As[n][kk + 7] = a1.w;
        }
        // ---- stage W chunk: KC x 128 floats ----
        {
            const float* wp = W + (size_t)kc * 128;
            #pragma unroll
            for (int i = 0; i < 4; i++) {
                int idx  = tid * 4 + i;         // float4 index 0..1023
                int row  = idx >> 5;            // 0..31
                int colf = (idx & 31) * 4;      // 0..124
                float4 wv = *reinterpret_cast<const float4*>(wp + row * 128 + colf);
                *reinterpret_cast<float4*>(&Ws[row][colf]) = wv;
            }
        }
        __syncthreads();

        for (int kk = 0; kk < KC; kk++) {
            float a[4];
            #pragma unroll
            for (int i = 0; i < 4; i++) a[i] = As[n0 + i][kk];
            float4 w0 = *reinterpret_cast<const float4*>(&Ws[kk][j0]);
            float4 w1 = *reinterpret_cast<const float4*>(&Ws[kk][j0 + 4]);
            float w[8] = {w0.x, w0.y, w0.z, w0.w, w1.x, w1.y, w1.z, w1.w};
            #pragma unroll
            for (int i = 0; i < 4; i++)
                #pragma unroll
                for (int j = 0; j < 8; j++)
                    acc[i][j] += a[i] * w[j];
        }
        __syncthreads();
    }

    // ---- epilogue: relu + store ----
    #pragma unroll
    for (int i = 0; i < 4; i++) {
        int n = block_n0 + n0 + i;
        if (n >= N_NODES) break;
        float* op = out + (size_t)n * D + j0;
        float4 o0, o1;
        o0.x = fmaxf(acc[i][0], 0.f); o0.y = fmaxf(acc[i][1], 0.f);
        o0.z = fmaxf(acc[i][2], 0.f); o0.w = fmaxf(acc[i][3], 0.f);
        o1.x = fmaxf(acc[i][4], 0.f); o1.y = fmaxf(acc[i][5], 0.f);
        o1.z = fmaxf(acc[i][6], 0.f); o1.w = fmaxf(acc[i][7], 0.f);
        *reinterpret_cast<float4*>(op)     = o0;
        *reinterpret_cast<float4*>(op + 4) = o1;
    }
}

// ---------------------------------------------------------------------------
extern "C" void kernel_launch(void* const* d_in, const int* in_sizes, int n_in,
                              void* d_out, int out_size, void* d_ws, size_t ws_size,
                              hipStream_t stream)
{
    const float* x    = (const float*)d_in[0];
    const int*   rows = (const int*)  d_in[1];
    const int*   cols = (const int*)  d_in[2];
    const float* vals = (const float*)d_in[3];
    const float* W    = (const float*)d_in[4];
    float* out = (float*)d_out;
    float* h   = (float*)d_ws;   // [N_NODES][D] fp32 scratch = 51.2 MB

    // zero h (ws is poisoned 0xAA before every call)
    hipMemsetAsync(h, 0, (size_t)N_NODES * D * sizeof(float), stream);

    // scatter: 32 threads per edge
    {
        long long total = (long long)N_EDGES * 32;
        int blocks = (int)((total + 255) / 256);
        scatter_kernel<<<blocks, 256, 0, stream>>>(x, rows, cols, vals, h);
    }

    // fused GEMM + relu
    {
        int blocks = (N_NODES + 63) / 64;
        gemm_relu_kernel<<<blocks, 256, 0, stream>>>(h, x, W, out);
    }
}

// Round 2
// 340.789 us; speedup vs baseline: 3.5647x; 3.5647x over previous
//
#include <hip/hip_runtime.h>

constexpr int N_NODES = 100000;
constexpr int N_EDGES = 600000;
constexpr int D = 128;          // feature dim; OUT_DIM is also 128
constexpr int KC = 32;          // k-chunk for GEMM staging

constexpr int SCAN_CHUNK = 1024;                                       // elements per scan block
constexpr int N_SCAN_BLOCKS = (N_NODES + SCAN_CHUNK - 1) / SCAN_CHUNK; // 98

// ---------------- workspace layout (bytes) ----------------
constexpr size_t H_OFF      = 0;                       // [N][D] float      = 51,200,000
constexpr size_t RS_OFF     = 51200000;                // row_start: 100001 ints
constexpr size_t CUR_OFF    = 51600128;                // cursor:    100000 ints
constexpr size_t BS_OFF     = 52000256;                // block_sums: 128 ints
constexpr size_t EDGES_OFF  = 52000768;                // int2 x 600000 = 4.8 MB
constexpr size_t COUNTS_OFF = 56800768;                // counts: 100000 ints  (end ~57.2 MB)

// ---------------------------------------------------------------------------
// CSR build pass 1: per-row edge counts
// ---------------------------------------------------------------------------
__global__ __launch_bounds__(256) void histogram_kernel(
    const int* __restrict__ rows, int* __restrict__ counts)
{
    int e = blockIdx.x * blockDim.x + threadIdx.x;
    if (e < N_EDGES) atomicAdd(&counts[rows[e]], 1);
}

// ---------------------------------------------------------------------------
// CSR build pass 2a: per-chunk exclusive scan (1024 counts / block)
// ---------------------------------------------------------------------------
__global__ __launch_bounds__(256) void scan_blocks_kernel(
    const int* __restrict__ counts, int* __restrict__ row_start,
    int* __restrict__ block_sums)
{
    __shared__ int sdata[256];
    const int b = blockIdx.x, t = threadIdx.x;
    const int base = b * SCAN_CHUNK + t * 4;
    int v[4];
    #pragma unroll
    for (int i = 0; i < 4; i++) {
        int idx = base + i;
        v[i] = (idx < N_NODES) ? counts[idx] : 0;
    }
    int tsum = v[0] + v[1] + v[2] + v[3];
    sdata[t] = tsum;
    __syncthreads();
    for (int off = 1; off < 256; off <<= 1) {
        int val = (t >= off) ? sdata[t - off] : 0;
        __syncthreads();
        sdata[t] += val;
        __syncthreads();
    }
    if (t == 255) block_sums[b] = sdata[255];
    int run = sdata[t] - tsum;    // exclusive prefix of this thread
    #pragma unroll
    for (int i = 0; i < 4; i++) {
        int idx = base + i;
        if (idx < N_NODES) row_start[idx] = run;
        run += v[i];
    }
}

// ---------------------------------------------------------------------------
// CSR build pass 2b: scan the 98 block sums (single block)
// ---------------------------------------------------------------------------
__global__ __launch_bounds__(128) void scan_top_kernel(int* __restrict__ block_sums)
{
    __shared__ int sdata[128];
    const int t = threadIdx.x;
    int v = (t < N_SCAN_BLOCKS) ? block_sums[t] : 0;
    sdata[t] = v;
    __syncthreads();
    for (int off = 1; off < 128; off <<= 1) {
        int val = (t >= off) ? sdata[t - off] : 0;
        __syncthreads();
        sdata[t] += val;
        __syncthreads();
    }
    if (t < N_SCAN_BLOCKS) block_sums[t] = sdata[t] - v;   // exclusive
}

// ---------------------------------------------------------------------------
// CSR build pass 2c: add chunk offsets; init cursor; terminate row_start
// ---------------------------------------------------------------------------
__global__ __launch_bounds__(256) void add_offsets_kernel(
    int* __restrict__ row_start, const int* __restrict__ block_sums,
    int* __restrict__ cursor)
{
    int i = blockIdx.x * blockDim.x + threadIdx.x;
    if (i < N_NODES) {
        int v = row_start[i] + block_sums[i >> 10];
        row_start[i] = v;
        cursor[i]    = v;
    }
    if (i == 0) row_start[N_NODES] = N_EDGES;
}

// ---------------------------------------------------------------------------
// CSR build pass 3: reorder edges into row-sorted (col, val) pairs
// ---------------------------------------------------------------------------
__global__ __launch_bounds__(256) void reorder_kernel(
    const int* __restrict__ rows, const int* __restrict__ cols,
    const float* __restrict__ vals, int* __restrict__ cursor,
    int2* __restrict__ edges)
{
    int e = blockIdx.x * blockDim.x + threadIdx.x;
    if (e >= N_EDGES) return;
    int pos = atomicAdd(&cursor[rows[e]], 1);
    edges[pos] = make_int2(cols[e], __float_as_int(vals[e]));
}

// ---------------------------------------------------------------------------
// Aggregation (pull): one wave per node, 64 lanes x float2 = 128 features.
// h[n] = sum over edges of val * x[col]; written exactly once, no atomics.
// ---------------------------------------------------------------------------
__global__ __launch_bounds__(256) void aggregate_kernel(
    const float* __restrict__ x, const int* __restrict__ row_start,
    const int2* __restrict__ edges, float* __restrict__ h)
{
    const int wave = threadIdx.x >> 6;
    const int lane = threadIdx.x & 63;
    const int n = blockIdx.x * 4 + wave;
    if (n >= N_NODES) return;

    const int s = row_start[n];
    const int t = row_start[n + 1];
    float2 acc = {0.f, 0.f};
    for (int i = s; i < t; i++) {
        int2 e = edges[i];                       // uniform across wave -> broadcast
        float v = __int_as_float(e.y);
        float2 xv = *reinterpret_cast<const float2*>(x + (size_t)e.x * D + lane * 2);
        acc.x += v * xv.x;
        acc.y += v * xv.y;
    }
    *reinterpret_cast<float2*>(h + (size_t)n * D + lane * 2) = acc;
}

// ---------------------------------------------------------------------------
// out = relu(h @ W[0:128] + x @ W[128:256])
// Block tile: 64 nodes x 128 outputs, 256 threads, per-thread 4x8 register tile.
// ---------------------------------------------------------------------------
__global__ __launch_bounds__(256) void gemm_relu_kernel(
    const float* __restrict__ h,
    const float* __restrict__ x,
    const float* __restrict__ W,   // [256][128]
    float*       __restrict__ out)
{
    __shared__ float As[64][KC + 1];   // +1 pad breaks bank conflicts
    __shared__ float Ws[KC][128];

    const int block_n0 = blockIdx.x * 64;
    const int tid = threadIdx.x;
    const int tx = tid & 15;          // 16 j-groups of 8
    const int ty = tid >> 4;          // 16 node-groups of 4
    const int j0 = tx * 8;
    const int n0 = ty * 4;

    float acc[4][8];
    #pragma unroll
    for (int i = 0; i < 4; i++)
        #pragma unroll
        for (int j = 0; j < 8; j++) acc[i][j] = 0.f;

    for (int kc = 0; kc < 2 * D; kc += KC) {
        {
            const float* src = (kc < D) ? h : x;
            const int kbase = kc & (D - 1);
            const int n  = tid >> 2;            // 0..63
            const int kk = (tid & 3) * 8;       // 0,8,16,24
            int nn = block_n0 + n;
            if (nn >= N_NODES) nn = N_NODES - 1;
            const float* sp = src + (size_t)nn * D + kbase + kk;
            float4 a0 = *reinterpret_cast<const float4*>(sp);
            float4 a1 = *reinterpret_cast<const float4*>(sp + 4);
            As[n][kk + 0] = a0.x; As[n][kk + 1] = a0.y;
            As[n][kk + 2] = a0.z; As[n][kk + 3] = a0.w;
            As[n][kk + 4] = a1.x; As[n][kk + 5] = a1.y;
            As[n][kk + 6] = a1.z; As[n][kk + 7] = a1.w;
        }
        {
            const float* wp = W + (size_t)kc * 128;
            #pragma unroll
            for (int i = 0; i < 4; i++) {
                int idx  = tid * 4 + i;
                int row  = idx >> 5;
                int colf = (idx & 31) * 4;
                float4 wv = *reinterpret_cast<const float4*>(wp + row * 128 + colf);
                *reinterpret_cast<float4*>(&Ws[row][colf]) = wv;
            }
        }
        __syncthreads();

        for (int kk = 0; kk < KC; kk++) {
            float a[4];
            #pragma unroll
            for (int i = 0; i < 4; i++) a[i] = As[n0 + i][kk];
            float4 w0 = *reinterpret_cast<const float4*>(&Ws[kk][j0]);
            float4 w1 = *reinterpret_cast<const float4*>(&Ws[kk][j0 + 4]);
            float w[8] = {w0.x, w0.y, w0.z, w0.w, w1.x, w1.y, w1.z, w1.w};
            #pragma unroll
            for (int i = 0; i < 4; i++)
                #pragma unroll
                for (int j = 0; j < 8; j++)
                    acc[i][j] += a[i] * w[j];
        }
        __syncthreads();
    }

    #pragma unroll
    for (int i = 0; i < 4; i++) {
        int n = block_n0 + n0 + i;
        if (n >= N_NODES) break;
        float* op = out + (size_t)n * D + j0;
        float4 o0, o1;
        o0.x = fmaxf(acc[i][0], 0.f); o0.y = fmaxf(acc[i][1], 0.f);
        o0.z = fmaxf(acc[i][2], 0.f); o0.w = fmaxf(acc[i][3], 0.f);
        o1.x = fmaxf(acc[i][4], 0.f); o1.y = fmaxf(acc[i][5], 0.f);
        o1.z = fmaxf(acc[i][6], 0.f); o1.w = fmaxf(acc[i][7], 0.f);
        *reinterpret_cast<float4*>(op)     = o0;
        *reinterpret_cast<float4*>(op + 4) = o1;
    }
}

// ---------------------------------------------------------------------------
extern "C" void kernel_launch(void* const* d_in, const int* in_sizes, int n_in,
                              void* d_out, int out_size, void* d_ws, size_t ws_size,
                              hipStream_t stream)
{
    const float* x    = (const float*)d_in[0];
    const int*   rows = (const int*)  d_in[1];
    const int*   cols = (const int*)  d_in[2];
    const float* vals = (const float*)d_in[3];
    const float* W    = (const float*)d_in[4];
    float* out = (float*)d_out;

    char* ws = (char*)d_ws;
    float* h          = (float*)(ws + H_OFF);
    int*   row_start  = (int*)  (ws + RS_OFF);
    int*   cursor     = (int*)  (ws + CUR_OFF);
    int*   block_sums = (int*)  (ws + BS_OFF);
    int2*  edges      = (int2*) (ws + EDGES_OFF);
    int*   counts     = (int*)  (ws + COUNTS_OFF);

    // zero the histogram (ws is poisoned 0xAA before every call)
    hipMemsetAsync(counts, 0, N_NODES * sizeof(int), stream);

    histogram_kernel  <<<(N_EDGES + 255) / 256, 256, 0, stream>>>(rows, counts);
    scan_blocks_kernel<<<N_SCAN_BLOCKS, 256, 0, stream>>>(counts, row_start, block_sums);
    scan_top_kernel   <<<1, 128, 0, stream>>>(block_sums);
    add_offsets_kernel<<<(N_NODES + 255) / 256, 256, 0, stream>>>(row_start, block_sums, cursor);
    reorder_kernel    <<<(N_EDGES + 255) / 256, 256, 0, stream>>>(rows, cols, vals, cursor, edges);
    aggregate_kernel  <<<(N_NODES + 3) / 4, 256, 0, stream>>>(x, row_start, edges, h);
    gemm_relu_kernel  <<<(N_NODES + 63) / 64, 256, 0, stream>>>(h, x, W, out);
}

// Round 3
// 254.899 us; speedup vs baseline: 4.7658x; 1.3370x over previous
//
#include <hip/hip_runtime.h>
#include <hip/hip_bf16.h>

constexpr int N_NODES = 100000;
constexpr int N_EDGES = 600000;
constexpr int D = 128;          // feature dim; OUT_DIM is also 128

constexpr int SCAN_CHUNK = 1024;
constexpr int N_SCAN_BLOCKS = (N_NODES + SCAN_CHUNK - 1) / SCAN_CHUNK; // 98

// ---------------- workspace layout (bytes) ----------------
// counts aliases the head of the edges buffer: counts is dead after
// scan_blocks_kernel reads it; edges is first written by reorder_kernel later.
constexpr size_t X16_OFF    = 0;          // x  in bf16: 100000*128*2 = 25,600,000
constexpr size_t H16_OFF    = 25600000;   // h  in bf16: 25,600,000
constexpr size_t WP_OFF     = 51200000;   // packed W bf16: 65,536
constexpr size_t RS_OFF     = 51265664;   // row_start: 100001 ints
constexpr size_t CUR_OFF    = 51665792;   // cursor: 100000 ints
constexpr size_t BS_OFF     = 52065792;   // block_sums: 128 ints
constexpr size_t EDGES_OFF  = 52066304;   // int2 x 600000 = 4.8 MB (end ~56.9 MB)
constexpr size_t COUNTS_OFF = EDGES_OFF;  // aliased (disjoint lifetime)

typedef __attribute__((ext_vector_type(8))) short short8;
typedef __attribute__((ext_vector_type(4))) float float4v;

__device__ inline unsigned short f2bf(float f) {
    union { float f; unsigned int u; } v; v.f = f;
    unsigned int u = v.u + 0x7fffu + ((v.u >> 16) & 1u);  // RNE
    return (unsigned short)(u >> 16);
}
__device__ inline float bf2f(unsigned int lo16) {
    union { unsigned int u; float f; } v; v.u = lo16 << 16;
    return v.f;
}

// ---------------------------------------------------------------------------
// x fp32 -> bf16 (packed pairs in uint)
// ---------------------------------------------------------------------------
__global__ __launch_bounds__(256) void cast_x_kernel(
    const float* __restrict__ x, uint4* __restrict__ x16)
{
    int g = blockIdx.x * 256 + threadIdx.x;          // 8-float groups
    if (g >= N_NODES * D / 8) return;
    const float4* xp = reinterpret_cast<const float4*>(x + (size_t)g * 8);
    float4 a = xp[0], b = xp[1];
    uint4 o;
    o.x = (unsigned int)f2bf(a.x) | ((unsigned int)f2bf(a.y) << 16);
    o.y = (unsigned int)f2bf(a.z) | ((unsigned int)f2bf(a.w) << 16);
    o.z = (unsigned int)f2bf(b.x) | ((unsigned int)f2bf(b.y) << 16);
    o.w = (unsigned int)f2bf(b.z) | ((unsigned int)f2bf(b.w) << 16);
    x16[g] = o;
}

// ---------------------------------------------------------------------------
// Pack W [256][128] fp32 -> bf16 in B-fragment order for mfma_f32_16x16x32_bf16.
// GEMM reads: b_frag[lane][j] = W[s*32 + (lane>>4)*8 + j][jt*16 + (lane&15)]
// at linear index ((s*8 + jt)*64 + lane)*8 + j.
// ---------------------------------------------------------------------------
__global__ __launch_bounds__(256) void pack_w_kernel(
    const float* __restrict__ W, unsigned short* __restrict__ Wp)
{
    int idx = blockIdx.x * 256 + threadIdx.x;        // 0..32767
    if (idx >= 8 * 8 * 64 * 8) return;
    int j    = idx & 7;
    int lane = (idx >> 3) & 63;
    int jt   = (idx >> 9) & 7;
    int s    = idx >> 12;
    int k = s * 32 + (lane >> 4) * 8 + j;
    int n = jt * 16 + (lane & 15);
    Wp[idx] = f2bf(W[k * 128 + n]);
}

// ---------------------------------------------------------------------------
// CSR build pass 1: per-row edge counts
// ---------------------------------------------------------------------------
__global__ __launch_bounds__(256) void histogram_kernel(
    const int* __restrict__ rows, int* __restrict__ counts)
{
    int e = blockIdx.x * blockDim.x + threadIdx.x;
    if (e < N_EDGES) atomicAdd(&counts[rows[e]], 1);
}

// ---------------------------------------------------------------------------
// CSR build pass 2a: per-chunk exclusive scan (1024 counts / block)
// ---------------------------------------------------------------------------
__global__ __launch_bounds__(256) void scan_blocks_kernel(
    const int* __restrict__ counts, int* __restrict__ row_start,
    int* __restrict__ block_sums)
{
    __shared__ int sdata[256];
    const int b = blockIdx.x, t = threadIdx.x;
    const int base = b * SCAN_CHUNK + t * 4;
    int v[4];
    #pragma unroll
    for (int i = 0; i < 4; i++) {
        int idx = base + i;
        v[i] = (idx < N_NODES) ? counts[idx] : 0;
    }
    int tsum = v[0] + v[1] + v[2] + v[3];
    sdata[t] = tsum;
    __syncthreads();
    for (int off = 1; off < 256; off <<= 1) {
        int val = (t >= off) ? sdata[t - off] : 0;
        __syncthreads();
        sdata[t] += val;
        __syncthreads();
    }
    if (t == 255) block_sums[b] = sdata[255];
    int run = sdata[t] - tsum;
    #pragma unroll
    for (int i = 0; i < 4; i++) {
        int idx = base + i;
        if (idx < N_NODES) row_start[idx] = run;
        run += v[i];
    }
}

// ---------------------------------------------------------------------------
// CSR build pass 2b: scan the 98 block sums (single block)
// ---------------------------------------------------------------------------
__global__ __launch_bounds__(128) void scan_top_kernel(int* __restrict__ block_sums)
{
    __shared__ int sdata[128];
    const int t = threadIdx.x;
    int v = (t < N_SCAN_BLOCKS) ? block_sums[t] : 0;
    sdata[t] = v;
    __syncthreads();
    for (int off = 1; off < 128; off <<= 1) {
        int val = (t >= off) ? sdata[t - off] : 0;
        __syncthreads();
        sdata[t] += val;
        __syncthreads();
    }
    if (t < N_SCAN_BLOCKS) block_sums[t] = sdata[t] - v;
}

// ---------------------------------------------------------------------------
// CSR build pass 2c: add chunk offsets; init cursor; terminate row_start
// ---------------------------------------------------------------------------
__global__ __launch_bounds__(256) void add_offsets_kernel(
    int* __restrict__ row_start, const int* __restrict__ block_sums,
    int* __restrict__ cursor)
{
    int i = blockIdx.x * blockDim.x + threadIdx.x;
    if (i < N_NODES) {
        int v = row_start[i] + block_sums[i >> 10];
        row_start[i] = v;
        cursor[i]    = v;
    }
    if (i == 0) row_start[N_NODES] = N_EDGES;
}

// ---------------------------------------------------------------------------
// CSR build pass 3: reorder edges into row-sorted (col, val) pairs
// ---------------------------------------------------------------------------
__global__ __launch_bounds__(256) void reorder_kernel(
    const int* __restrict__ rows, const int* __restrict__ cols,
    const float* __restrict__ vals, int* __restrict__ cursor,
    int2* __restrict__ edges)
{
    int e = blockIdx.x * blockDim.x + threadIdx.x;
    if (e >= N_EDGES) return;
    int pos = atomicAdd(&cursor[rows[e]], 1);
    edges[pos] = make_int2(cols[e], __float_as_int(vals[e]));
}

// ---------------------------------------------------------------------------
// Aggregation (pull): one wave per node, 64 lanes x 2 bf16 = 128 features.
// Gathers bf16 x rows (256 B/edge), accumulates fp32, writes bf16 h once.
// ---------------------------------------------------------------------------
__global__ __launch_bounds__(256) void aggregate_kernel(
    const unsigned int* __restrict__ x16, const int* __restrict__ row_start,
    const int2* __restrict__ edges, unsigned int* __restrict__ h16)
{
    const int wave = threadIdx.x >> 6;
    const int lane = threadIdx.x & 63;
    const int n = blockIdx.x * 4 + wave;
    if (n >= N_NODES) return;

    const int s = row_start[n];
    const int t = row_start[n + 1];
    float ax = 0.f, ay = 0.f;
    int i = s;
    for (; i + 1 < t; i += 2) {
        int2 e0 = edges[i];
        int2 e1 = edges[i + 1];
        unsigned int p0 = x16[(size_t)e0.x * 64 + lane];
        unsigned int p1 = x16[(size_t)e1.x * 64 + lane];
        float v0 = __int_as_float(e0.y);
        float v1 = __int_as_float(e1.y);
        ax += v0 * bf2f(p0 & 0xffffu) + v1 * bf2f(p1 & 0xffffu);
        ay += v0 * bf2f(p0 >> 16)     + v1 * bf2f(p1 >> 16);
    }
    if (i < t) {
        int2 e = edges[i];
        unsigned int p = x16[(size_t)e.x * 64 + lane];
        float v = __int_as_float(e.y);
        ax += v * bf2f(p & 0xffffu);
        ay += v * bf2f(p >> 16);
    }
    h16[(size_t)n * 64 + lane] = (unsigned int)f2bf(ax) | ((unsigned int)f2bf(ay) << 16);
}

// ---------------------------------------------------------------------------
// out = relu([h|x] @ W) via mfma_f32_16x16x32_bf16. No LDS.
// Block = 4 waves; wave covers 16 rows x 128 cols (8 col-tiles, 8 k-steps).
// A-frag loaded straight from global (h for k<128, x for k>=128);
// B-frag from pre-packed Wp (lane-contiguous 16 B, L2-resident).
// C/D layout: col = lane&15, row = (lane>>4)*4 + reg  [m89-verified].
// ---------------------------------------------------------------------------
__global__ __launch_bounds__(256) void gemm_mfma_kernel(
    const unsigned short* __restrict__ h16,
    const unsigned short* __restrict__ x16,
    const unsigned short* __restrict__ Wp,
    float* __restrict__ out)
{
    const int lane = threadIdx.x & 63;
    const int wave = threadIdx.x >> 6;
    const int m    = lane & 15;
    const int quad = lane >> 4;
    const int row0 = blockIdx.x * 64 + wave * 16;

    int arow = row0 + m;
    if (arow >= N_NODES) arow = N_NODES - 1;   // clamped dup load; stores guarded

    const unsigned short* hrow = h16 + (size_t)arow * D + quad * 8;
    const unsigned short* xrow = x16 + (size_t)arow * D + quad * 8;

    float4v acc[8];
    #pragma unroll
    for (int jt = 0; jt < 8; jt++) acc[jt] = (float4v){0.f, 0.f, 0.f, 0.f};

    #pragma unroll
    for (int s = 0; s < 8; s++) {
        const unsigned short* ap = (s < 4) ? (hrow + s * 32) : (xrow + (s - 4) * 32);
        short8 a = *reinterpret_cast<const short8*>(ap);
        #pragma unroll
        for (int jt = 0; jt < 8; jt++) {
            short8 b = *reinterpret_cast<const short8*>(
                Wp + ((size_t)((s * 8 + jt) * 64 + lane)) * 8);
            acc[jt] = __builtin_amdgcn_mfma_f32_16x16x32_bf16(a, b, acc[jt], 0, 0, 0);
        }
    }

    #pragma unroll
    for (int reg = 0; reg < 4; reg++) {
        int r = row0 + quad * 4 + reg;
        if (r < N_NODES) {
            float* orow = out + (size_t)r * D;
            #pragma unroll
            for (int jt = 0; jt < 8; jt++)
                orow[jt * 16 + m] = fmaxf(acc[jt][reg], 0.f);
        }
    }
}

// ---------------------------------------------------------------------------
extern "C" void kernel_launch(void* const* d_in, const int* in_sizes, int n_in,
                              void* d_out, int out_size, void* d_ws, size_t ws_size,
                              hipStream_t stream)
{
    const float* x    = (const float*)d_in[0];
    const int*   rows = (const int*)  d_in[1];
    const int*   cols = (const int*)  d_in[2];
    const float* vals = (const float*)d_in[3];
    const float* W    = (const float*)d_in[4];
    float* out = (float*)d_out;

    char* ws = (char*)d_ws;
    unsigned int*   x16u  = (unsigned int*)  (ws + X16_OFF);
    unsigned short* x16s  = (unsigned short*)(ws + X16_OFF);
    unsigned int*   h16u  = (unsigned int*)  (ws + H16_OFF);
    unsigned short* h16s  = (unsigned short*)(ws + H16_OFF);
    unsigned short* Wp    = (unsigned short*)(ws + WP_OFF);
    int*   row_start  = (int*)  (ws + RS_OFF);
    int*   cursor     = (int*)  (ws + CUR_OFF);
    int*   block_sums = (int*)  (ws + BS_OFF);
    int2*  edges      = (int2*) (ws + EDGES_OFF);
    int*   counts     = (int*)  (ws + COUNTS_OFF);   // aliases edges head

    hipMemsetAsync(counts, 0, N_NODES * sizeof(int), stream);

    cast_x_kernel     <<<(N_NODES * D / 8 + 255) / 256, 256, 0, stream>>>(x, (uint4*)x16u);
    pack_w_kernel     <<<(32768 + 255) / 256, 256, 0, stream>>>(W, Wp);
    histogram_kernel  <<<(N_EDGES + 255) / 256, 256, 0, stream>>>(rows, counts);
    scan_blocks_kernel<<<N_SCAN_BLOCKS, 256, 0, stream>>>(counts, row_start, block_sums);
    scan_top_kernel   <<<1, 128, 0, stream>>>(block_sums);
    add_offsets_kernel<<<(N_NODES + 255) / 256, 256, 0, stream>>>(row_start, block_sums, cursor);
    reorder_kernel    <<<(N_EDGES + 255) / 256, 256, 0, stream>>>(rows, cols, vals, cursor, edges);
    aggregate_kernel  <<<(N_NODES + 3) / 4, 256, 0, stream>>>(x16u, row_start, edges, h16u);
    gemm_mfma_kernel  <<<(N_NODES + 63) / 64, 256, 0, stream>>>(h16s, x16s, Wp, out);
}

// Round 4
// 229.447 us; speedup vs baseline: 5.2944x; 1.1109x over previous
//
#include <hip/hip_runtime.h>
#include <hip/hip_bf16.h>

constexpr int N_NODES = 100000;
constexpr int N_EDGES = 600000;
constexpr int D = 128;          // feature dim; OUT_DIM is also 128

constexpr int SCAN_CHUNK = 1024;
constexpr int N_SCAN_BLOCKS = (N_NODES + SCAN_CHUNK - 1) / SCAN_CHUNK; // 98

constexpr int CAST_BLOCKS = (N_NODES * D / 8) / 256;   // 6250 (exact)
constexpr int PACK_BLOCKS = 32768 / 256;               // 128

// ---------------- workspace layout (bytes) ----------------
// counts aliases the head of the edges buffer (disjoint lifetimes:
// counts dead after scan_blocks; edges first written by reorder).
constexpr size_t X16_OFF    = 0;          // x bf16: 100000*128*2 = 25,600,000
constexpr size_t WP_OFF     = 25600000;   // packed W bf16: 65,536
constexpr size_t RS_OFF     = 25665536;   // row_start: 100001 ints (pad to 400128)
constexpr size_t CUR_OFF    = 26065664;   // cursor: 100000 ints
constexpr size_t BS_OFF     = 26465664;   // block_sums: 128 ints
constexpr size_t EDGES_OFF  = 26466176;   // int2 x 600000 = 4.8 MB (end ~31.3 MB)
constexpr size_t COUNTS_OFF = EDGES_OFF;  // aliased

typedef __attribute__((ext_vector_type(8))) short short8;
typedef __attribute__((ext_vector_type(4))) float float4v;

__device__ inline unsigned short f2bf(float f) {
    union { float f; unsigned int u; } v; v.f = f;
    unsigned int u = v.u + 0x7fffu + ((v.u >> 16) & 1u);  // RNE
    return (unsigned short)(u >> 16);
}
__device__ inline float bf2f(unsigned int lo16) {
    union { unsigned int u; float f; } v; v.u = lo16 << 16;
    return v.f;
}

// ---------------------------------------------------------------------------
// Fused prep: blocks [0,6250) cast x fp32->bf16; blocks [6250,6378) pack W.
// Wp B-fragment order for mfma_f32_16x16x32_bf16:
//   b_frag[lane][j] = W[s*32 + (lane>>4)*8 + j][jt*16 + (lane&15)]
//   at linear index ((s*8 + jt)*64 + lane)*8 + j.
// ---------------------------------------------------------------------------
__global__ __launch_bounds__(256) void prep_kernel(
    const float* __restrict__ x, uint4* __restrict__ x16,
    const float* __restrict__ W, unsigned short* __restrict__ Wp)
{
    int b = blockIdx.x;
    if (b < CAST_BLOCKS) {
        int g = b * 256 + threadIdx.x;               // 8-float group
        const float4* xp = reinterpret_cast<const float4*>(x + (size_t)g * 8);
        float4 a = xp[0], c = xp[1];
        uint4 o;
        o.x = (unsigned int)f2bf(a.x) | ((unsigned int)f2bf(a.y) << 16);
        o.y = (unsigned int)f2bf(a.z) | ((unsigned int)f2bf(a.w) << 16);
        o.z = (unsigned int)f2bf(c.x) | ((unsigned int)f2bf(c.y) << 16);
        o.w = (unsigned int)f2bf(c.z) | ((unsigned int)f2bf(c.w) << 16);
        x16[(size_t)g / 2 * 2 + (g & 1)] = o;        // == x16[g]
    } else {
        int idx = (b - CAST_BLOCKS) * 256 + threadIdx.x;   // 0..32767
        int j    = idx & 7;
        int lane = (idx >> 3) & 63;
        int jt   = (idx >> 9) & 7;
        int s    = idx >> 12;
        int k = s * 32 + (lane >> 4) * 8 + j;
        int n = jt * 16 + (lane & 15);
        Wp[idx] = f2bf(W[k * 128 + n]);
    }
}

// ---------------------------------------------------------------------------
// CSR build pass 1: per-row edge counts
// ---------------------------------------------------------------------------
__global__ __launch_bounds__(256) void histogram_kernel(
    const int* __restrict__ rows, int* __restrict__ counts)
{
    int e = blockIdx.x * blockDim.x + threadIdx.x;
    if (e < N_EDGES) atomicAdd(&counts[rows[e]], 1);
}

// ---------------------------------------------------------------------------
// CSR build pass 2a: per-chunk exclusive scan (1024 counts / block)
// ---------------------------------------------------------------------------
__global__ __launch_bounds__(256) void scan_blocks_kernel(
    const int* __restrict__ counts, int* __restrict__ row_start,
    int* __restrict__ block_sums)
{
    __shared__ int sdata[256];
    const int b = blockIdx.x, t = threadIdx.x;
    const int base = b * SCAN_CHUNK + t * 4;
    int v[4];
    #pragma unroll
    for (int i = 0; i < 4; i++) {
        int idx = base + i;
        v[i] = (idx < N_NODES) ? counts[idx] : 0;
    }
    int tsum = v[0] + v[1] + v[2] + v[3];
    sdata[t] = tsum;
    __syncthreads();
    for (int off = 1; off < 256; off <<= 1) {
        int val = (t >= off) ? sdata[t - off] : 0;
        __syncthreads();
        sdata[t] += val;
        __syncthreads();
    }
    if (t == 255) block_sums[b] = sdata[255];
    int run = sdata[t] - tsum;
    #pragma unroll
    for (int i = 0; i < 4; i++) {
        int idx = base + i;
        if (idx < N_NODES) row_start[idx] = run;
        run += v[i];
    }
}

// ---------------------------------------------------------------------------
// CSR build pass 2b: scan the 98 block sums (single block)
// ---------------------------------------------------------------------------
__global__ __launch_bounds__(128) void scan_top_kernel(int* __restrict__ block_sums)
{
    __shared__ int sdata[128];
    const int t = threadIdx.x;
    int v = (t < N_SCAN_BLOCKS) ? block_sums[t] : 0;
    sdata[t] = v;
    __syncthreads();
    for (int off = 1; off < 128; off <<= 1) {
        int val = (t >= off) ? sdata[t - off] : 0;
        __syncthreads();
        sdata[t] += val;
        __syncthreads();
    }
    if (t < N_SCAN_BLOCKS) block_sums[t] = sdata[t] - v;
}

// ---------------------------------------------------------------------------
// CSR build pass 2c: add chunk offsets; init cursor; terminate row_start
// ---------------------------------------------------------------------------
__global__ __launch_bounds__(256) void add_offsets_kernel(
    int* __restrict__ row_start, const int* __restrict__ block_sums,
    int* __restrict__ cursor)
{
    int i = blockIdx.x * blockDim.x + threadIdx.x;
    if (i < N_NODES) {
        int v = row_start[i] + block_sums[i >> 10];
        row_start[i] = v;
        cursor[i]    = v;
    }
    if (i == 0) row_start[N_NODES] = N_EDGES;
}

// ---------------------------------------------------------------------------
// CSR build pass 3: reorder edges into row-sorted (col, val) pairs
// ---------------------------------------------------------------------------
__global__ __launch_bounds__(256) void reorder_kernel(
    const int* __restrict__ rows, const int* __restrict__ cols,
    const float* __restrict__ vals, int* __restrict__ cursor,
    int2* __restrict__ edges)
{
    int e = blockIdx.x * blockDim.x + threadIdx.x;
    if (e >= N_EDGES) return;
    int pos = atomicAdd(&cursor[rows[e]], 1);
    edges[pos] = make_int2(cols[e], __float_as_int(vals[e]));
}

// ---------------------------------------------------------------------------
// Fused aggregate + GEMM + relu.
// Block = 4 waves = 64 rows; wave w owns rows row0 = blk*64 + w*16 .. +15.
//
// Phase A: wave splits into 4 groups of 16 lanes; group g, t-slot processes
// node m_local = t*4 + g (m parity varies with g -> conflict-free LDS writes).
// Lane gl of a group gathers uint4 = features [gl*8..gl*8+7] of x16[col],
// accumulates fp32, packs bf16, writes one 16B A-frag piece to LDS at
// frag index s*64 + m*4 + q  (s = gl>>2, q = gl&3). Both ds_write_b128 and
// ds_read_b128 tile all 32 banks at the 8-access/bank b128 baseline.
//
// Phase B: mfma_f32_16x16x32_bf16; A s=0..3 from LDS (= h rows), s=4..7
// straight from global x16; B from pre-packed Wp (lane-contiguous 16B, L2).
// C/D layout: col = lane&15, row = (lane>>4)*4 + reg  [m89-verified, R3-passed].
// ---------------------------------------------------------------------------
__global__ __launch_bounds__(256) void fused_agg_gemm_kernel(
    const uint4* __restrict__ x16v,
    const unsigned short* __restrict__ x16s,
    const int* __restrict__ row_start,
    const int2* __restrict__ edges,
    const unsigned short* __restrict__ Wp,
    float* __restrict__ out)
{
    __shared__ uint4 lds4[4 * 256];   // wave*256 + s*64 + m*4 + q  (16 KB)

    const int tid  = threadIdx.x;
    const int wave = tid >> 6;
    const int lane = tid & 63;
    const int row0 = blockIdx.x * 64 + wave * 16;

    // ---------------- Phase A: aggregate 16 rows into LDS ----------------
    {
        const int g   = lane >> 4;      // group 0..3
        const int gl  = lane & 15;      // lane in group
        const int s_w = gl >> 2;
        const int q_w = gl & 3;
        for (int t = 0; t < 4; t++) {
            const int m_local = t * 4 + g;
            const int n = row0 + m_local;
            float a0=0.f,a1=0.f,a2=0.f,a3=0.f,a4=0.f,a5=0.f,a6=0.f,a7=0.f;
            if (n < N_NODES) {
                int i = row_start[n];
                const int e_end = row_start[n + 1];
                for (; i + 1 < e_end; i += 2) {
                    int2 e0 = edges[i];
                    int2 e1 = edges[i + 1];
                    float v0 = __int_as_float(e0.y);
                    float v1 = __int_as_float(e1.y);
                    uint4 p0 = x16v[(size_t)e0.x * 16 + gl];
                    uint4 p1 = x16v[(size_t)e1.x * 16 + gl];
                    a0 += v0 * bf2f(p0.x & 0xffffu) + v1 * bf2f(p1.x & 0xffffu);
                    a1 += v0 * bf2f(p0.x >> 16)     + v1 * bf2f(p1.x >> 16);
                    a2 += v0 * bf2f(p0.y & 0xffffu) + v1 * bf2f(p1.y & 0xffffu);
                    a3 += v0 * bf2f(p0.y >> 16)     + v1 * bf2f(p1.y >> 16);
                    a4 += v0 * bf2f(p0.z & 0xffffu) + v1 * bf2f(p1.z & 0xffffu);
                    a5 += v0 * bf2f(p0.z >> 16)     + v1 * bf2f(p1.z >> 16);
                    a6 += v0 * bf2f(p0.w & 0xffffu) + v1 * bf2f(p1.w & 0xffffu);
                    a7 += v0 * bf2f(p0.w >> 16)     + v1 * bf2f(p1.w >> 16);
                }
                if (i < e_end) {
                    int2 e0 = edges[i];
                    float v0 = __int_as_float(e0.y);
                    uint4 p0 = x16v[(size_t)e0.x * 16 + gl];
                    a0 += v0 * bf2f(p0.x & 0xffffu);
                    a1 += v0 * bf2f(p0.x >> 16);
                    a2 += v0 * bf2f(p0.y & 0xffffu);
                    a3 += v0 * bf2f(p0.y >> 16);
                    a4 += v0 * bf2f(p0.z & 0xffffu);
                    a5 += v0 * bf2f(p0.z >> 16);
                    a6 += v0 * bf2f(p0.w & 0xffffu);
                    a7 += v0 * bf2f(p0.w >> 16);
                }
            }
            uint4 o;
            o.x = (unsigned int)f2bf(a0) | ((unsigned int)f2bf(a1) << 16);
            o.y = (unsigned int)f2bf(a2) | ((unsigned int)f2bf(a3) << 16);
            o.z = (unsigned int)f2bf(a4) | ((unsigned int)f2bf(a5) << 16);
            o.w = (unsigned int)f2bf(a6) | ((unsigned int)f2bf(a7) << 16);
            lds4[wave * 256 + s_w * 64 + m_local * 4 + q_w] = o;
        }
    }
    __syncthreads();   // (wave-private region; barrier kept for safety)

    // ---------------- Phase B: MFMA GEMM + relu ----------------
    const int m    = lane & 15;
    const int quad = lane >> 4;

    int arow = row0 + m;
    if (arow >= N_NODES) arow = N_NODES - 1;   // clamped dup load; stores guarded
    const unsigned short* xrow = x16s + (size_t)arow * D + quad * 8;

    float4v acc[8];
    #pragma unroll
    for (int jt = 0; jt < 8; jt++) acc[jt] = (float4v){0.f, 0.f, 0.f, 0.f};

    #pragma unroll
    for (int s = 0; s < 8; s++) {
        short8 a;
        if (s < 4)
            a = *reinterpret_cast<const short8*>(&lds4[wave * 256 + s * 64 + m * 4 + quad]);
        else
            a = *reinterpret_cast<const short8*>(xrow + (s - 4) * 32);
        #pragma unroll
        for (int jt = 0; jt < 8; jt++) {
            short8 b = *reinterpret_cast<const short8*>(
                Wp + ((size_t)((s * 8 + jt) * 64 + lane)) * 8);
            acc[jt] = __builtin_amdgcn_mfma_f32_16x16x32_bf16(a, b, acc[jt], 0, 0, 0);
        }
    }

    #pragma unroll
    for (int reg = 0; reg < 4; reg++) {
        int r = row0 + quad * 4 + reg;
        if (r < N_NODES) {
            float* orow = out + (size_t)r * D;
            #pragma unroll
            for (int jt = 0; jt < 8; jt++)
                orow[jt * 16 + m] = fmaxf(acc[jt][reg], 0.f);
        }
    }
}

// ---------------------------------------------------------------------------
extern "C" void kernel_launch(void* const* d_in, const int* in_sizes, int n_in,
                              void* d_out, int out_size, void* d_ws, size_t ws_size,
                              hipStream_t stream)
{
    const float* x    = (const float*)d_in[0];
    const int*   rows = (const int*)  d_in[1];
    const int*   cols = (const int*)  d_in[2];
    const float* vals = (const float*)d_in[3];
    const float* W    = (const float*)d_in[4];
    float* out = (float*)d_out;

    char* ws = (char*)d_ws;
    uint4*          x16v  = (uint4*)         (ws + X16_OFF);
    unsigned short* x16s  = (unsigned short*)(ws + X16_OFF);
    unsigned short* Wp    = (unsigned short*)(ws + WP_OFF);
    int*   row_start  = (int*)  (ws + RS_OFF);
    int*   cursor     = (int*)  (ws + CUR_OFF);
    int*   block_sums = (int*)  (ws + BS_OFF);
    int2*  edges      = (int2*) (ws + EDGES_OFF);
    int*   counts     = (int*)  (ws + COUNTS_OFF);   // aliases edges head

    hipMemsetAsync(counts, 0, N_NODES * sizeof(int), stream);

    prep_kernel       <<<CAST_BLOCKS + PACK_BLOCKS, 256, 0, stream>>>(x, x16v, W, Wp);
    histogram_kernel  <<<(N_EDGES + 255) / 256, 256, 0, stream>>>(rows, counts);
    scan_blocks_kernel<<<N_SCAN_BLOCKS, 256, 0, stream>>>(counts, row_start, block_sums);
    scan_top_kernel   <<<1, 128, 0, stream>>>(block_sums);
    add_offsets_kernel<<<(N_NODES + 255) / 256, 256, 0, stream>>>(row_start, block_sums, cursor);
    reorder_kernel    <<<(N_EDGES + 255) / 256, 256, 0, stream>>>(rows, cols, vals, cursor, edges);
    fused_agg_gemm_kernel<<<(N_NODES + 63) / 64, 256, 0, stream>>>(
        x16v, x16s, row_start, edges, Wp, out);
}